// Round 7
// baseline (1003.789 us; speedup 1.0000x reference)
//
#include <hip/hip_runtime.h>

#define S_   2048
#define D_   1024
#define H_   16
#define HD_  64
#define B_   2
#define BH_  32
#define M_   4096
#define SCALE 0.125f
#define NTRI 528   /* 32*33/2 lower-tri 64x64 tiles per bh */

typedef short s8v  __attribute__((ext_vector_type(8)));
typedef float f4v  __attribute__((ext_vector_type(4)));
typedef unsigned short us4v __attribute__((ext_vector_type(4)));
typedef unsigned short us8v __attribute__((ext_vector_type(8)));

__device__ inline unsigned short f2b(float f) {           // fp32 -> bf16 RNE
    unsigned u = __builtin_bit_cast(unsigned, f);
    return (unsigned short)((u + 0x7fffu + ((u >> 16) & 1u)) >> 16);
}

__device__ inline void tri_map(int L, int& qt, int& kt) { // L -> (qt, kt<=qt)
    int q = (int)((sqrtf(8.0f * (float)L + 1.0f) - 1.0f) * 0.5f);
    while ((q + 1) * (q + 2) / 2 <= L) ++q;
    while (q * (q + 1) / 2 > L) --q;
    qt = q; kt = L - q * (q + 1) / 2;
}

// ---------------------------------------------------------------------------
__global__ __launch_bounds__(256) void conv_x(const float* __restrict__ in,
                                              unsigned short* __restrict__ out) {
    int i = blockIdx.x * 256 + threadIdx.x;
    float4 v = ((const float4*)in)[i];
    us4v o = { f2b(v.x), f2b(v.y), f2b(v.z), f2b(v.w) };
    *(us4v*)&out[(size_t)i * 4] = o;
}

// ---------------------------------------------------------------------------
__global__ __launch_bounds__(256) void convT(
    const float* __restrict__ W0, const float* __restrict__ W1,
    const float* __restrict__ W2, const float* __restrict__ W3,
    unsigned short* __restrict__ WtAll) {
    const int z = blockIdx.z;
    const float* W = (z == 0) ? W0 : (z == 1) ? W1 : (z == 2) ? W2 : W3;
    unsigned short* Wt = WtAll + (size_t)z * D_ * D_;
    __shared__ unsigned short Tb[64][65];
    const int t = threadIdx.x;
    const int r0 = blockIdx.y * 64, c0 = blockIdx.x * 64;
    #pragma unroll
    for (int j = 0; j < 4; ++j) {
        int v = j * 256 + t; int r = v >> 4, c4 = (v & 15) * 4;
        float4 wv = *(const float4*)&W[(size_t)(r0 + r) * D_ + c0 + c4];
        Tb[r][c4 + 0] = f2b(wv.x); Tb[r][c4 + 1] = f2b(wv.y);
        Tb[r][c4 + 2] = f2b(wv.z); Tb[r][c4 + 3] = f2b(wv.w);
    }
    __syncthreads();
    #pragma unroll
    for (int j = 0; j < 2; ++j) {
        int v = j * 256 + t; int c = v >> 3, r8 = (v & 7) * 8;
        us8v o;
        #pragma unroll
        for (int i = 0; i < 8; ++i) o[i] = Tb[r8 + i][c];
        *(us8v*)&Wt[(size_t)(c0 + c) * D_ + r0 + r8] = o;
    }
}

// ---------------------------------------------------------------------------
// QKV projection, bf16 MFMA.  grid (8, 32, 3), 256 thr, tile 128x128, BK=64.
// ---------------------------------------------------------------------------
__global__ __launch_bounds__(256) void qkv_mfma(
    const unsigned short* __restrict__ xb, const unsigned short* __restrict__ WtAll,
    unsigned short* __restrict__ Qb, unsigned short* __restrict__ Kb,
    unsigned short* __restrict__ Vt) {
    const int z = blockIdx.z;
    const unsigned short* Wp = WtAll + (size_t)z * D_ * D_;
    const int bm = blockIdx.y, bn = blockIdx.x;
    const int t = threadIdx.x;
    const int w = t >> 6, lane = t & 63;
    const int lg = lane >> 4, lid = lane & 15;
    const int wm = w >> 1, wn = w & 1;

    __shared__ unsigned short As[128][72];
    __shared__ unsigned short Bs[128][72];

    const f4v z4 = {0.f, 0.f, 0.f, 0.f};
    f4v acc[4][4];
    #pragma unroll
    for (int mf = 0; mf < 4; ++mf)
        #pragma unroll
        for (int nf = 0; nf < 4; ++nf) acc[mf][nf] = z4;

    for (int bk = 0; bk < 16; ++bk) {
        #pragma unroll
        for (int j = 0; j < 4; ++j) {
            int v = j * 256 + t; int r = v >> 3, c8 = (v & 7) * 8;
            *(us8v*)&As[r][c8] = *(const us8v*)&xb[(size_t)(bm * 128 + r) * D_ + bk * 64 + c8];
            *(us8v*)&Bs[r][c8] = *(const us8v*)&Wp[(size_t)(bn * 128 + r) * D_ + bk * 64 + c8];
        }
        __syncthreads();
        #pragma unroll
        for (int kk = 0; kk < 2; ++kk) {
            s8v af[4], bf[4];
            #pragma unroll
            for (int mf = 0; mf < 4; ++mf)
                af[mf] = *(const s8v*)&As[wm * 64 + mf * 16 + lid][kk * 32 + lg * 8];
            #pragma unroll
            for (int nf = 0; nf < 4; ++nf)
                bf[nf] = *(const s8v*)&Bs[wn * 64 + nf * 16 + lid][kk * 32 + lg * 8];
            #pragma unroll
            for (int mf = 0; mf < 4; ++mf)
                #pragma unroll
                for (int nf = 0; nf < 4; ++nf)
                    acc[mf][nf] = __builtin_amdgcn_mfma_f32_16x16x32_bf16(
                        af[mf], bf[nf], acc[mf][nf], 0, 0, 0);
        }
        __syncthreads();
    }

    const int rbase = lg * 4;
    if (z == 2) {                       // V -> transposed [bh][d][s]
        #pragma unroll
        for (int mf = 0; mf < 4; ++mf) {
            const int m0 = bm * 128 + wm * 64 + mf * 16 + rbase;
            const int b = m0 >> 11, s0 = m0 & (S_ - 1);
            #pragma unroll
            for (int nf = 0; nf < 4; ++nf) {
                const int n = bn * 128 + wn * 64 + nf * 16 + lid;
                const int h = n >> 6, d = n & 63;
                us4v o;
                #pragma unroll
                for (int r = 0; r < 4; ++r) o[r] = f2b(acc[mf][nf][r]);
                *(us4v*)&Vt[((size_t)((b * H_ + h) * HD_ + d)) * S_ + s0] = o;
            }
        }
    } else {
        unsigned short* O = (z == 0) ? Qb : Kb;   // [bh][s][d]
        #pragma unroll
        for (int mf = 0; mf < 4; ++mf) {
            #pragma unroll
            for (int r = 0; r < 4; ++r) {
                const int m = bm * 128 + wm * 64 + mf * 16 + rbase + r;
                const int b = m >> 11, s = m & (S_ - 1);
                #pragma unroll
                for (int nf = 0; nf < 4; ++nf) {
                    const int n = bn * 128 + wn * 64 + nf * 16 + lid;
                    const int h = n >> 6, d = n & 63;
                    O[((size_t)((b * H_ + h) * S_ + s)) * HD_ + d] = f2b(acc[mf][nf][r]);
                }
            }
        }
    }
}

// ---------------------------------------------------------------------------
// zero rowsum [BH][S] fp32.  grid 64 x 256 thr x float4.
// ---------------------------------------------------------------------------
__global__ __launch_bounds__(256) void zero_rowsum(float* __restrict__ p) {
    int i = blockIdx.x * 256 + threadIdx.x;
    ((float4*)p)[i] = make_float4(0.f, 0.f, 0.f, 0.f);
}

// ---------------------------------------------------------------------------
// denom: per lower-tri tile (bh, qt, kt): QK^T, exp, row-sum -> atomicAdd.
// grid (32, 528), 256 thr = 4 waves, each wave 16 q rows.
// ---------------------------------------------------------------------------
__global__ __launch_bounds__(256) void denom_k(
    const unsigned short* __restrict__ Qb, const unsigned short* __restrict__ Kb,
    float* __restrict__ rowsum) {
    const int bh = blockIdx.x;
    int qt, kt; tri_map(blockIdx.y, qt, kt);
    const int t = threadIdx.x, w = t >> 6, lane = t & 63;
    const int lg = lane >> 4, lid = lane & 15;

    const unsigned short* Qp = Qb + ((size_t)bh * S_ + qt * 64 + w * 16 + lid) * HD_;
    const s8v qf0 = *(const s8v*)&Qp[lg * 8];
    const s8v qf1 = *(const s8v*)&Qp[32 + lg * 8];
    const unsigned short* Kbase = Kb + (size_t)bh * S_ * HD_;

    const f4v z4 = {0.f, 0.f, 0.f, 0.f};
    f4v sacc[4];
    #pragma unroll
    for (int nf = 0; nf < 4; ++nf) sacc[nf] = z4;
    #pragma unroll
    for (int nf = 0; nf < 4; ++nf) {
        const unsigned short* Kr = Kbase + ((size_t)(kt * 64 + nf * 16 + lid)) * HD_;
        s8v b0 = *(const s8v*)&Kr[lg * 8];
        s8v b1 = *(const s8v*)&Kr[32 + lg * 8];
        sacc[nf] = __builtin_amdgcn_mfma_f32_16x16x32_bf16(qf0, b0, sacc[nf], 0, 0, 0);
        sacc[nf] = __builtin_amdgcn_mfma_f32_16x16x32_bf16(qf1, b1, sacc[nf], 0, 0, 0);
    }
    const bool diag = (kt == qt);
    #pragma unroll
    for (int r = 0; r < 4; ++r) {
        const int qrow = qt * 64 + w * 16 + lg * 4 + r;
        float s = 0.f;
        #pragma unroll
        for (int nf = 0; nf < 4; ++nf) {
            float e = __expf(sacc[nf][r] * SCALE);
            if (diag && (kt * 64 + nf * 16 + lid) > qrow) e = 0.f;
            s += e;
        }
        #pragma unroll
        for (int mk = 8; mk; mk >>= 1) s += __shfl_xor(s, mk);
        if (lid == 0) atomicAdd(&rowsum[(size_t)bh * S_ + qrow], s);
    }
}

// ---------------------------------------------------------------------------
// ztail: zero-fill attn cols [(qt+1)*64, S) for 64 rows.  grid (32, 32).
// ---------------------------------------------------------------------------
__global__ __launch_bounds__(256) void ztail(float* __restrict__ attn) {
    const int bh = blockIdx.x, qt = blockIdx.y;
    float* abase = attn + (size_t)bh * S_ * S_;
    const int t = threadIdx.x;
    const int row = t >> 2;
    const float4 zz = make_float4(0.f, 0.f, 0.f, 0.f);
    for (int c = (qt + 1) * 64 + (t & 3) * 4; c < S_; c += 16)
        *(float4*)&attn[(size_t)bh * S_ * S_ + (size_t)(qt * 64 + row) * S_ + c] = zz;
    (void)abase;
}

// ---------------------------------------------------------------------------
// pwrite: per lower-tri tile: recompute QK^T, p = exp*inv, LDS-stage,
// coalesced float4 stores to attn.  grid (32, 528).
// ---------------------------------------------------------------------------
__global__ __launch_bounds__(256) void pwrite(
    const unsigned short* __restrict__ Qb, const unsigned short* __restrict__ Kb,
    const float* __restrict__ rowsum, float* __restrict__ attn) {
    const int bh = blockIdx.x;
    int qt, kt; tri_map(blockIdx.y, qt, kt);
    const int t = threadIdx.x, w = t >> 6, lane = t & 63;
    const int lg = lane >> 4, lid = lane & 15;

    __shared__ float Pf[64][68];

    const unsigned short* Qp = Qb + ((size_t)bh * S_ + qt * 64 + w * 16 + lid) * HD_;
    const s8v qf0 = *(const s8v*)&Qp[lg * 8];
    const s8v qf1 = *(const s8v*)&Qp[32 + lg * 8];
    const unsigned short* Kbase = Kb + (size_t)bh * S_ * HD_;

    const f4v z4 = {0.f, 0.f, 0.f, 0.f};
    f4v sacc[4];
    #pragma unroll
    for (int nf = 0; nf < 4; ++nf) sacc[nf] = z4;
    #pragma unroll
    for (int nf = 0; nf < 4; ++nf) {
        const unsigned short* Kr = Kbase + ((size_t)(kt * 64 + nf * 16 + lid)) * HD_;
        s8v b0 = *(const s8v*)&Kr[lg * 8];
        s8v b1 = *(const s8v*)&Kr[32 + lg * 8];
        sacc[nf] = __builtin_amdgcn_mfma_f32_16x16x32_bf16(qf0, b0, sacc[nf], 0, 0, 0);
        sacc[nf] = __builtin_amdgcn_mfma_f32_16x16x32_bf16(qf1, b1, sacc[nf], 0, 0, 0);
    }
    const bool diag = (kt == qt);
    #pragma unroll
    for (int r = 0; r < 4; ++r) {
        const int qrow = qt * 64 + w * 16 + lg * 4 + r;
        const float inv = 1.0f / rowsum[(size_t)bh * S_ + qrow];
        #pragma unroll
        for (int nf = 0; nf < 4; ++nf) {
            float p = __expf(sacc[nf][r] * SCALE) * inv;
            if (diag && (kt * 64 + nf * 16 + lid) > qrow) p = 0.f;
            Pf[w * 16 + lg * 4 + r][nf * 16 + lid] = p;
        }
    }
    __syncthreads();
    {
        const int row = t >> 2, c0 = t & 3;
        float* dst = &attn[(size_t)bh * S_ * S_ + (size_t)(qt * 64 + row) * S_ + kt * 64];
        #pragma unroll
        for (int i = 0; i < 4; ++i) {
            const int c4 = c0 + i * 4;
            *(float4*)&dst[c4 * 4] = *(const float4*)&Pf[row][c4 * 4];
        }
    }
}

// ---------------------------------------------------------------------------
// pv: ctx = attn @ V per (bh, qt), reading normalized P fp32 -> bf16 frags.
// grid (32, 32), qt heavy-first.  Writes ctxb bf16 [b][s][h*64+d].
// ---------------------------------------------------------------------------
__global__ __launch_bounds__(256) void pv_k(
    const float* __restrict__ attn, const unsigned short* __restrict__ Vt,
    unsigned short* __restrict__ ctxb) {
    const int bh = blockIdx.x;
    const int qt = 31 - (int)blockIdx.y;          // heavy blocks first
    const int t = threadIdx.x, w = t >> 6, lane = t & 63;
    const int lg = lane >> 4, lid = lane & 15;

    const float* Pr = attn + (size_t)bh * S_ * S_ + (size_t)(qt * 64 + w * 16 + lid) * S_;
    const unsigned short* Vbase = Vt + (size_t)bh * HD_ * S_;

    const f4v z4 = {0.f, 0.f, 0.f, 0.f};
    f4v cacc[4];
    #pragma unroll
    for (int nf = 0; nf < 4; ++nf) cacc[nf] = z4;

    for (int kt = 0; kt <= qt; ++kt) {
        // A-frags: P row (fp32) -> bf16x8, k = kt*64 + {0,32} + lg*8
        float4 a0 = *(const float4*)&Pr[kt * 64 + lg * 8];
        float4 a1 = *(const float4*)&Pr[kt * 64 + lg * 8 + 4];
        float4 a2 = *(const float4*)&Pr[kt * 64 + 32 + lg * 8];
        float4 a3 = *(const float4*)&Pr[kt * 64 + 32 + lg * 8 + 4];
        s8v pa0 = { (short)f2b(a0.x), (short)f2b(a0.y), (short)f2b(a0.z), (short)f2b(a0.w),
                    (short)f2b(a1.x), (short)f2b(a1.y), (short)f2b(a1.z), (short)f2b(a1.w) };
        s8v pa1 = { (short)f2b(a2.x), (short)f2b(a2.y), (short)f2b(a2.z), (short)f2b(a2.w),
                    (short)f2b(a3.x), (short)f2b(a3.y), (short)f2b(a3.z), (short)f2b(a3.w) };
        #pragma unroll
        for (int nf = 0; nf < 4; ++nf) {
            const unsigned short* Vr = &Vbase[((size_t)(nf * 16 + lid)) * S_ + kt * 64];
            s8v vb0 = *(const s8v*)&Vr[lg * 8];
            s8v vb1 = *(const s8v*)&Vr[32 + lg * 8];
            cacc[nf] = __builtin_amdgcn_mfma_f32_16x16x32_bf16(pa0, vb0, cacc[nf], 0, 0, 0);
            cacc[nf] = __builtin_amdgcn_mfma_f32_16x16x32_bf16(pa1, vb1, cacc[nf], 0, 0, 0);
        }
    }

    const int b = bh >> 4, h = bh & (H_ - 1);
    #pragma unroll
    for (int nf = 0; nf < 4; ++nf) {
        #pragma unroll
        for (int r = 0; r < 4; ++r) {
            const int s = qt * 64 + w * 16 + lg * 4 + r;
            ctxb[((size_t)(b * S_ + s)) * D_ + h * HD_ + nf * 16 + lid] = f2b(cacc[nf][r]);
        }
    }
}

// ---------------------------------------------------------------------------
// out = ctx(bf16) @ Wo + bo -> fp32.  grid (8, 32).
// ---------------------------------------------------------------------------
__global__ __launch_bounds__(256) void out_mfma(
    const unsigned short* __restrict__ ctxb, const unsigned short* __restrict__ Wot,
    const float* __restrict__ bo, float* __restrict__ out) {
    const int bm = blockIdx.y, bn = blockIdx.x;
    const int t = threadIdx.x;
    const int w = t >> 6, lane = t & 63;
    const int lg = lane >> 4, lid = lane & 15;
    const int wm = w >> 1, wn = w & 1;

    __shared__ unsigned short As[128][72];
    __shared__ unsigned short Bs[128][72];

    const f4v z4 = {0.f, 0.f, 0.f, 0.f};
    f4v acc[4][4];
    #pragma unroll
    for (int mf = 0; mf < 4; ++mf)
        #pragma unroll
        for (int nf = 0; nf < 4; ++nf) acc[mf][nf] = z4;

    for (int bk = 0; bk < 16; ++bk) {
        #pragma unroll
        for (int j = 0; j < 4; ++j) {
            int v = j * 256 + t; int r = v >> 3, c8 = (v & 7) * 8;
            *(us8v*)&As[r][c8] = *(const us8v*)&ctxb[(size_t)(bm * 128 + r) * D_ + bk * 64 + c8];
            *(us8v*)&Bs[r][c8] = *(const us8v*)&Wot[(size_t)(bn * 128 + r) * D_ + bk * 64 + c8];
        }
        __syncthreads();
        #pragma unroll
        for (int kk = 0; kk < 2; ++kk) {
            s8v af[4], bf[4];
            #pragma unroll
            for (int mf = 0; mf < 4; ++mf)
                af[mf] = *(const s8v*)&As[wm * 64 + mf * 16 + lid][kk * 32 + lg * 8];
            #pragma unroll
            for (int nf = 0; nf < 4; ++nf)
                bf[nf] = *(const s8v*)&Bs[wn * 64 + nf * 16 + lid][kk * 32 + lg * 8];
            #pragma unroll
            for (int mf = 0; mf < 4; ++mf)
                #pragma unroll
                for (int nf = 0; nf < 4; ++nf)
                    acc[mf][nf] = __builtin_amdgcn_mfma_f32_16x16x32_bf16(
                        af[mf], bf[nf], acc[mf][nf], 0, 0, 0);
        }
        __syncthreads();
    }

    #pragma unroll
    for (int mf = 0; mf < 4; ++mf) {
        #pragma unroll
        for (int r = 0; r < 4; ++r) {
            const int m = bm * 128 + wm * 64 + mf * 16 + lg * 4 + r;
            #pragma unroll
            for (int nf = 0; nf < 4; ++nf) {
                const int n = bn * 128 + wn * 64 + nf * 16 + lid;
                out[(size_t)m * D_ + n] = acc[mf][nf][r] + bo[n];
            }
        }
    }
}

// ---------------------------------------------------------------------------
extern "C" void kernel_launch(void* const* d_in, const int* in_sizes, int n_in,
                              void* d_out, int out_size, void* d_ws, size_t ws_size,
                              hipStream_t stream) {
    const float* x  = (const float*)d_in[0];
    const float* Wq = (const float*)d_in[1];
    const float* Wk = (const float*)d_in[2];
    const float* Wv = (const float*)d_in[3];
    const float* Wo = (const float*)d_in[4];
    const float* bo = (const float*)d_in[5];

    float* out  = (float*)d_out;                       // [B,S,D] fp32
    float* attn = out + (size_t)M_ * D_;               // [B,H,S,S] fp32

    unsigned short* ws   = (unsigned short*)d_ws;
    unsigned short* xb   = ws;                           // [M][D] bf16
    unsigned short* Wt   = xb + (size_t)M_ * D_;         // [4][D][D] bf16 ([n][k])
    unsigned short* Qb   = Wt + (size_t)4 * D_ * D_;     // [BH][S][HD]
    unsigned short* Kb   = Qb + (size_t)M_ * D_;         // [BH][S][HD]
    unsigned short* Vt   = Kb + (size_t)M_ * D_;         // [BH][HD][S]
    unsigned short* ctxb = Vt + (size_t)M_ * D_;         // [M][D]
    float* rowsum        = (float*)(ctxb + (size_t)M_ * D_);  // [BH][S]

    conv_x<<<dim3((M_ * D_) / 4 / 256), 256, 0, stream>>>(x, xb);
    convT<<<dim3(16, 16, 4), 256, 0, stream>>>(Wq, Wk, Wv, Wo, Wt);
    qkv_mfma<<<dim3(8, 32, 3), 256, 0, stream>>>(xb, Wt, Qb, Kb, Vt);
    zero_rowsum<<<dim3((BH_ * S_) / 4 / 256), 256, 0, stream>>>(rowsum);
    denom_k<<<dim3(BH_, NTRI), 256, 0, stream>>>(Qb, Kb, rowsum);
    ztail<<<dim3(BH_, 32), 256, 0, stream>>>(attn);
    pwrite<<<dim3(BH_, NTRI), 256, 0, stream>>>(Qb, Kb, rowsum, attn);
    pv_k<<<dim3(BH_, 32), 256, 0, stream>>>(attn, Vt, ctxb);
    out_mfma<<<dim3(8, 32), 256, 0, stream>>>(ctxb, Wt + (size_t)3 * D_ * D_, bo, out);
}